// Round 22
// baseline (209.389 us; speedup 1.0000x reference)
//
#include <hip/hip_runtime.h>

#define Bc 2
#define Sc 2048
#define Dc 1024
#define Hc 16
#define HDc 64
#define NROWS 4096  // B*S
#define LOG2E 1.44269504f

typedef __attribute__((ext_vector_type(8))) _Float16 f16x8;
typedef __attribute__((ext_vector_type(4))) _Float16 f16x4;
typedef __attribute__((ext_vector_type(2))) __fp16 fp16v2;
typedef __attribute__((ext_vector_type(4))) float f32x4;
typedef __attribute__((ext_vector_type(16))) float f32x16;

__device__ __forceinline__ float ex2(float x) {
  return __builtin_amdgcn_exp2f(x);   // single v_exp_f32
}

// ---------------------------------------------------------------------------
// prep: fused fp32->f16 convert (feats, wq, wk, wv, wo).
// ---------------------------------------------------------------------------
__global__ __launch_bounds__(256)
void prep(const float* __restrict__ f,  const float* __restrict__ wq,
          const float* __restrict__ wk, const float* __restrict__ wv,
          const float* __restrict__ wo_,
          _Float16* __restrict__ fh, _Float16* __restrict__ wh3,
          _Float16* __restrict__ woh)
{
  int blk = blockIdx.x;
  const float* src; _Float16* hi; int base;
  if (blk < 4096)      { src = f;   hi = fh;            base = blk; }
  else if (blk < 5120) { src = wq;  hi = wh3;           base = blk - 4096; }
  else if (blk < 6144) { src = wk;  hi = wh3 + 1048576; base = blk - 5120; }
  else if (blk < 7168) { src = wv;  hi = wh3 + 2097152; base = blk - 6144; }
  else                 { src = wo_; hi = woh;           base = blk - 7168; }
  int i = base * 256 + threadIdx.x;
  float4 v = reinterpret_cast<const float4*>(src)[i];
  f16x4 h;
  h[0] = (_Float16)v.x; h[1] = (_Float16)v.y;
  h[2] = (_Float16)v.z; h[3] = (_Float16)v.w;
  reinterpret_cast<f16x4*>(hi)[i] = h;
}

// ---------------------------------------------------------------------------
// Fused QKV f16 GEMM + mask zero-scan preamble (hidden under compute).
// ---------------------------------------------------------------------------
__global__ __launch_bounds__(256, 4)
void gemm_qkv(const _Float16* __restrict__ Ah, const _Float16* __restrict__ Wh,
              const float* __restrict__ bq, const float* __restrict__ bk,
              const float* __restrict__ bv,
              _Float16* __restrict__ qb, _Float16* __restrict__ kb,
              _Float16* __restrict__ vtb,
              const float* __restrict__ mask, unsigned int* __restrict__ flag)
{
  __shared__ _Float16 Ash[128][40];
  __shared__ _Float16 Wsh[128][40];

  const int tid  = threadIdx.x;
  const int lane = tid & 63, wid = tid >> 6;
  const int l15  = lane & 15, l4 = lane >> 4;
  const int wr   = wid >> 1, wc = wid & 1;
  const int arow0 = blockIdx.x * 128;
  const int wrow0 = blockIdx.y * 128;

  {
    const int nthr = 768 * 256;
    int gtid = (blockIdx.y * gridDim.x + blockIdx.x) * 256 + tid;
    bool nz = false;
    for (int i = gtid; i < 2097152; i += nthr) {
      float4 mv = reinterpret_cast<const float4*>(mask)[i];
      nz = nz || (mv.x != 0.f) || (mv.y != 0.f) || (mv.z != 0.f) || (mv.w != 0.f);
    }
    if (__any(nz)) {
      if (lane == 0) atomicOr(flag, 1u);
    }
  }

  f32x4 acc[4][4];
#pragma unroll
  for (int m = 0; m < 4; ++m)
#pragma unroll
    for (int n = 0; n < 4; ++n) acc[m][n] = f32x4{0.f, 0.f, 0.f, 0.f};

  for (int k0 = 0; k0 < Dc; k0 += 32) {
    __syncthreads();
#pragma unroll
    for (int p = 0; p < 2; ++p) {
      int e = tid + 256 * p;
      int r = e >> 2, c8 = (e & 3) * 8;
      *reinterpret_cast<uint4*>(&Ash[r][c8]) =
          *reinterpret_cast<const uint4*>(Ah + (size_t)(arow0 + r) * Dc + k0 + c8);
      *reinterpret_cast<uint4*>(&Wsh[r][c8]) =
          *reinterpret_cast<const uint4*>(Wh + (size_t)(wrow0 + r) * Dc + k0 + c8);
    }
    __syncthreads();

    f16x8 bh[4];
#pragma unroll
    for (int n = 0; n < 4; ++n)
      bh[n] = *reinterpret_cast<const f16x8*>(&Wsh[wc * 64 + n * 16 + l15][l4 * 8]);
#pragma unroll
    for (int m = 0; m < 4; ++m) {
      f16x8 ah = *reinterpret_cast<const f16x8*>(&Ash[wr * 64 + m * 16 + l15][l4 * 8]);
#pragma unroll
      for (int n = 0; n < 4; ++n)
        acc[m][n] = __builtin_amdgcn_mfma_f32_16x16x32_f16(ah, bh[n], acc[m][n], 0, 0, 0);
    }
  }

#pragma unroll
  for (int m = 0; m < 4; ++m) {
#pragma unroll
    for (int n = 0; n < 4; ++n) {
      int cbase = wrow0 + wc * 64 + n * 16;
      int seg = cbase >> 10;
      int o = (cbase & 1023) + l15;
      int h = o >> 6, hd = o & 63;
      const float* bias = (seg == 0) ? bq : ((seg == 1) ? bk : bv);
      float bval = bias[o];
      float alpha = (seg == 0) ? (0.125f * LOG2E) : 1.0f;
      int r0 = arow0 + wr * 64 + m * 16 + l4 * 4;
      int b = r0 >> 11, s0 = r0 & (Sc - 1);
      if (seg == 2) {
        f16x4 pk;
#pragma unroll
        for (int reg = 0; reg < 4; ++reg)
          pk[reg] = (_Float16)((acc[m][n][reg] + bval) * alpha);
        *reinterpret_cast<f16x4*>(
            &vtb[(((size_t)b * Hc + h) * HDc + hd) * Sc + s0]) = pk;
      } else {
        _Float16* dst = (seg == 0) ? qb : kb;
#pragma unroll
        for (int reg = 0; reg < 4; ++reg) {
          float val = (acc[m][n][reg] + bval) * alpha;
          dst[(((size_t)b * Hc + h) * Sc + (s0 + reg)) * HDc + hd] = (_Float16)val;
        }
      }
    }
  }
}

// ---------------------------------------------------------------------------
// Output GEMM.
// ---------------------------------------------------------------------------
__global__ __launch_bounds__(256, 4)
void gemm_wo(const _Float16* __restrict__ Ah, const _Float16* __restrict__ Wh,
             const float* __restrict__ bias,
             float* __restrict__ out0, float* __restrict__ out1,
             const float* __restrict__ feats)
{
  __shared__ _Float16 Ash[64][40];
  __shared__ _Float16 Wsh[128][40];

  const int tid  = threadIdx.x;
  const int lane = tid & 63, wid = tid >> 6;
  const int l15  = lane & 15, l4 = lane >> 4;
  const int wr   = wid >> 1, wc = wid & 1;
  const int arow0 = blockIdx.x * 64;
  const int wrow0 = blockIdx.y * 128;

  f32x4 acc[2][4];
#pragma unroll
  for (int m = 0; m < 2; ++m)
#pragma unroll
    for (int n = 0; n < 4; ++n) acc[m][n] = f32x4{0.f, 0.f, 0.f, 0.f};

  for (int k0 = 0; k0 < Dc; k0 += 32) {
    __syncthreads();
    {
      int r = tid >> 2, c8 = (tid & 3) * 8;
      *reinterpret_cast<uint4*>(&Ash[r][c8]) =
          *reinterpret_cast<const uint4*>(Ah + (size_t)(arow0 + r) * Dc + k0 + c8);
    }
#pragma unroll
    for (int p = 0; p < 2; ++p) {
      int e = tid + 256 * p;
      int r = e >> 2, c8 = (e & 3) * 8;
      *reinterpret_cast<uint4*>(&Wsh[r][c8]) =
          *reinterpret_cast<const uint4*>(Wh + (size_t)(wrow0 + r) * Dc + k0 + c8);
    }
    __syncthreads();

    f16x8 bh[4];
#pragma unroll
    for (int n = 0; n < 4; ++n)
      bh[n] = *reinterpret_cast<const f16x8*>(&Wsh[wc * 64 + n * 16 + l15][l4 * 8]);
#pragma unroll
    for (int m = 0; m < 2; ++m) {
      f16x8 ah = *reinterpret_cast<const f16x8*>(&Ash[wr * 32 + m * 16 + l15][l4 * 8]);
#pragma unroll
      for (int n = 0; n < 4; ++n)
        acc[m][n] = __builtin_amdgcn_mfma_f32_16x16x32_f16(ah, bh[n], acc[m][n], 0, 0, 0);
    }
  }

#pragma unroll
  for (int m = 0; m < 2; ++m) {
#pragma unroll
    for (int n = 0; n < 4; ++n) {
      int c = wrow0 + wc * 64 + n * 16 + l15;
      float bval = bias[c];
#pragma unroll
      for (int reg = 0; reg < 4; ++reg) {
        int r = arow0 + wr * 32 + m * 16 + l4 * 4 + reg;
        float val = acc[m][n][reg] + bval;
        out1[(size_t)r * Dc + c] = val;
        out0[(size_t)r * Dc + c] = feats[(size_t)r * Dc + c] * val;
      }
    }
  }
}

// ---------------------------------------------------------------------------
// Flash attention, 32x32x16 f16 MFMA, INTRA-BLOCK KV-SPLIT:
// 8-wave (512-thr) blocks; waves 0-3 do KV[0:1024), waves 4-7 KV[1024:2048)
// for the same 128 q-rows. Grid 512 -> 16 waves/CU (was 8). Combine via LDS
// after the loop (flash split-K math, all intra-block). Exp2-domain softmax,
// defer-max, tree-max, zero-mask fast path, XCD-chunked swizzle.
// ---------------------------------------------------------------------------
#define QB 128
#define KB 64
#define NTH 16   // KV tiles per half

__global__ __launch_bounds__(512, 4)
void attn_mfma(const _Float16* __restrict__ q,
               const _Float16* __restrict__ k,
               const _Float16* __restrict__ vt,
               const float* __restrict__ mask,
               const unsigned int* __restrict__ mflag,
               _Float16* __restrict__ ctxh)
{
  __shared__ union {
    struct { _Float16 K[2][2][KB * 64]; _Float16 V[2][2][HDc * 64]; } kv;
    struct { float O[4][32][64]; float m0[4][32]; float l0_[4][32];
             float m1[4][32]; float l1_[4][32]; } ep;
  } sm;   // 64 KB

  const int tid  = threadIdx.x;
  const int lane = tid & 63;
  const int wq8  = tid >> 6;                 // 0..7
  const int g    = wq8 & 3;                  // q-row group (32 rows)
  const int half = wq8 >> 2;                 // KV half
  const int l31  = lane & 31;
  const int hi   = lane >> 5;

  const int nqb  = Sc / QB;                  // 16; grid = 512 = 8 XCD x 64
  const int bid  = blockIdx.x;
  const int swz  = (bid & 7) * 64 + (bid >> 3);   // XCD-chunked, bijective
  const int head = swz / nqb;
  const int q0   = (swz % nqb) * QB;
  const int b    = head / Hc;
  const int h    = head % Hc;
  const int kvb  = half * (Sc / 2);          // 0 or 1024

  const bool use_mask = (*mflag != 0u);

  const _Float16* kbase  = k  + (size_t)head * Sc * HDc;
  const _Float16* vtbase = vt + (size_t)head * HDc * Sc;
  const _Float16* qbase  = q  + ((size_t)head * Sc + q0 + g * 32 + l31) * HDc;
  const float*    mlh    = mask + ((size_t)b * Sc + q0 + g * 32 + l31) * Sc
                           + kvb + 4 * hi;

  // staging: 256 threads per half; each stages 2 chunks for K and V
  const int tidh = tid & 255;
  const int r0s = tidh >> 3, cs = tidh & 7;
  const int r1s = r0s + 32;
  const int so0 = r0s * 64 + ((cs ^ (r0s & 7)) * 8);
  const int so1 = r1s * 64 + ((cs ^ (r1s & 7)) * 8);

  f16x8 qf[4];
#pragma unroll
  for (int c = 0; c < 4; ++c)
    qf[c] = *reinterpret_cast<const f16x8*>(qbase + hi * 8 + 16 * c);

  f16x8 ones;
#pragma unroll
  for (int i = 0; i < 8; ++i) ones[i] = (_Float16)1.0f;

  f32x16 O0, O1, lacc;
#pragma unroll
  for (int i = 0; i < 16; ++i) { O0[i] = 0.f; O1[i] = 0.f; lacc[i] = 0.f; }
  float m_q = -3e38f;

  *reinterpret_cast<uint4*>(&sm.kv.K[half][0][so0]) =
      *reinterpret_cast<const uint4*>(kbase + (size_t)(kvb + r0s) * HDc + cs * 8);
  *reinterpret_cast<uint4*>(&sm.kv.K[half][0][so1]) =
      *reinterpret_cast<const uint4*>(kbase + (size_t)(kvb + r1s) * HDc + cs * 8);
  *reinterpret_cast<uint4*>(&sm.kv.V[half][0][so0]) =
      *reinterpret_cast<const uint4*>(vtbase + (size_t)r0s * Sc + kvb + cs * 8);
  *reinterpret_cast<uint4*>(&sm.kv.V[half][0][so1]) =
      *reinterpret_cast<const uint4*>(vtbase + (size_t)r1s * Sc + kvb + cs * 8);
  float4 mpf[8];
  if (use_mask) {
#pragma unroll
    for (int t2 = 0; t2 < 2; ++t2)
#pragma unroll
      for (int j = 0; j < 4; ++j)
        mpf[t2 * 4 + j] = *reinterpret_cast<const float4*>(mlh + 32 * t2 + 8 * j);
  }

  for (int kt = 0; kt < NTH; ++kt) {
    const int k0 = kt * KB;                  // offset within this half
    const int cur = kt & 1, nxt = cur ^ 1;
    __syncthreads();

    uint4 kr0, kr1, vr0, vr1;
    const bool pf = (kt + 1) < NTH;
    if (pf) {
      const int k1 = kvb + k0 + KB;
      kr0 = *reinterpret_cast<const uint4*>(kbase + (size_t)(k1 + r0s) * HDc + cs * 8);
      kr1 = *reinterpret_cast<const uint4*>(kbase + (size_t)(k1 + r1s) * HDc + cs * 8);
      vr0 = *reinterpret_cast<const uint4*>(vtbase + (size_t)r0s * Sc + k1 + cs * 8);
      vr1 = *reinterpret_cast<const uint4*>(vtbase + (size_t)r1s * Sc + k1 + cs * 8);
    }

    f32x16 s[2];
    __builtin_amdgcn_s_setprio(1);
#pragma unroll
    for (int t2 = 0; t2 < 2; ++t2) {
      f32x16 acc;
#pragma unroll
      for (int i = 0; i < 16; ++i) acc[i] = 0.f;
      const int krow = t2 * 32 + l31;
#pragma unroll
      for (int c = 0; c < 4; ++c) {
        const int ofs = krow * 64 + (((2 * c + hi) ^ (krow & 7)) * 8);
        acc = __builtin_amdgcn_mfma_f32_32x32x16_f16(
            *reinterpret_cast<const f16x8*>(&sm.kv.K[half][cur][ofs]), qf[c],
            acc, 0, 0, 0);
      }
      s[t2] = acc;
    }
    __builtin_amdgcn_s_setprio(0);

    if (use_mask) {
#pragma unroll
      for (int t2 = 0; t2 < 2; ++t2)
#pragma unroll
        for (int j = 0; j < 4; ++j) {
          float4 mv = mpf[t2 * 4 + j];
          s[t2][4 * j + 0] += mv.x * LOG2E; s[t2][4 * j + 1] += mv.y * LOG2E;
          s[t2][4 * j + 2] += mv.z * LOG2E; s[t2][4 * j + 3] += mv.w * LOG2E;
        }
      if (pf) {
#pragma unroll
        for (int t2 = 0; t2 < 2; ++t2)
#pragma unroll
          for (int j = 0; j < 4; ++j)
            mpf[t2 * 4 + j] = *reinterpret_cast<const float4*>(
                mlh + (k0 + KB) + 32 * t2 + 8 * j);
      }
    }

    // tree-max over this lane's 32 scores
    float t0_[8];
#pragma unroll
    for (int i = 0; i < 8; ++i)
      t0_[i] = fmaxf(fmaxf(s[0][2 * i], s[0][2 * i + 1]),
                     fmaxf(s[1][2 * i], s[1][2 * i + 1]));
    float t1_0 = fmaxf(fmaxf(t0_[0], t0_[1]), fmaxf(t0_[2], t0_[3]));
    float t1_1 = fmaxf(fmaxf(t0_[4], t0_[5]), fmaxf(t0_[6], t0_[7]));
    float lm = fmaxf(t1_0, t1_1);

    if (!__all(lm - m_q <= 8.0f * LOG2E)) {
      float vm = fmaxf(lm, __shfl_xor(lm, 32));
      float mn = fmaxf(m_q, vm);
      float cc = ex2(m_q - mn);
      m_q = mn;
#pragma unroll
      for (int reg = 0; reg < 16; ++reg) {
        int q_r = (reg & 3) + 8 * (reg >> 2) + 4 * hi;
        float ccr = __shfl(cc, q_r);
        O0[reg] *= ccr; O1[reg] *= ccr; lacc[reg] *= ccr;
      }
    }

    __builtin_amdgcn_s_setprio(1);
#pragma unroll
    for (int c = 0; c < 4; ++c) {
      const int t2 = c >> 1, rb = (c & 1) * 8;
      float p0 = ex2(s[t2][rb + 0] - m_q);
      float p1 = ex2(s[t2][rb + 1] - m_q);
      float p2 = ex2(s[t2][rb + 2] - m_q);
      float p3 = ex2(s[t2][rb + 3] - m_q);
      float p4 = ex2(s[t2][rb + 4] - m_q);
      float p5 = ex2(s[t2][rb + 5] - m_q);
      float p6 = ex2(s[t2][rb + 6] - m_q);
      float p7 = ex2(s[t2][rb + 7] - m_q);
      union { fp16v2 h; unsigned int u; } w0, w1, w2, w3;
      w0.h = __builtin_amdgcn_cvt_pkrtz(p0, p1);
      w1.h = __builtin_amdgcn_cvt_pkrtz(p2, p3);
      w2.h = __builtin_amdgcn_cvt_pkrtz(p4, p5);
      w3.h = __builtin_amdgcn_cvt_pkrtz(p6, p7);
      unsigned int u0 = w0.u, u1 = w1.u, u2 = w2.u, u3 = w3.u;
      asm("v_permlane32_swap_b32 %0, %1" : "+v"(u0), "+v"(u2));
      asm("v_permlane32_swap_b32 %0, %1" : "+v"(u1), "+v"(u3));
      union { unsigned int u[4]; f16x8 f; } pa;
      pa.u[0] = u0; pa.u[1] = u1; pa.u[2] = u2; pa.u[3] = u3;

      lacc = __builtin_amdgcn_mfma_f32_32x32x16_f16(pa.f, ones, lacc, 0, 0, 0);
      const int vofs = l31 * 64 + (((2 * c + hi) ^ (l31 & 7)) * 8);
      O0 = __builtin_amdgcn_mfma_f32_32x32x16_f16(
          pa.f, *reinterpret_cast<const f16x8*>(&sm.kv.V[half][cur][vofs]),
          O0, 0, 0, 0);
      O1 = __builtin_amdgcn_mfma_f32_32x32x16_f16(
          pa.f, *reinterpret_cast<const f16x8*>(&sm.kv.V[half][cur][vofs + 32 * 64]),
          O1, 0, 0, 0);
    }
    __builtin_amdgcn_s_setprio(0);

    if (pf) {
      *reinterpret_cast<uint4*>(&sm.kv.K[half][nxt][so0]) = kr0;
      *reinterpret_cast<uint4*>(&sm.kv.K[half][nxt][so1]) = kr1;
      *reinterpret_cast<uint4*>(&sm.kv.V[half][nxt][so0]) = vr0;
      *reinterpret_cast<uint4*>(&sm.kv.V[half][nxt][so1]) = vr1;
    }
  }

  // -------- intra-block combine of the two KV halves --------
  __syncthreads();   // all waves done reading kv region

  // publish m (row-consistent per wave) and l (column-uniform per reg)
  if (hi == 0) {
    if (half == 0) sm.ep.m0[g][l31] = m_q; else sm.ep.m1[g][l31] = m_q;
  }
  if (l31 == 0) {
#pragma unroll
    for (int reg = 0; reg < 16; ++reg) {
      int q_r = (reg & 3) + 8 * (reg >> 2) + 4 * hi;
      if (half == 0) sm.ep.l0_[g][q_r] = lacc[reg];
      else           sm.ep.l1_[g][q_r] = lacc[reg];
    }
  }
  // upper waves publish their O tile
  if (half == 1) {
#pragma unroll
    for (int reg = 0; reg < 16; ++reg) {
      int q_r = (reg & 3) + 8 * (reg >> 2) + 4 * hi;
      sm.ep.O[g][q_r][l31]      = O0[reg];
      sm.ep.O[g][q_r][32 + l31] = O1[reg];
    }
  }
  __syncthreads();

  if (half == 0) {
#pragma unroll
    for (int reg = 0; reg < 16; ++reg) {
      int q_r = (reg & 3) + 8 * (reg >> 2) + 4 * hi;
      float m0v = sm.ep.m0[g][q_r], m1v = sm.ep.m1[g][q_r];
      float l0v = lacc[reg],        l1v = sm.ep.l1_[g][q_r];
      float mm = fmaxf(m0v, m1v);
      float e0 = ex2(m0v - mm), e1 = ex2(m1v - mm);
      float inv = 1.0f / (l0v * e0 + l1v * e1);
      int row = q0 + g * 32 + q_r;
      size_t base = ((size_t)b * Sc + row) * Dc + h * HDc;
      ctxh[base + l31] =
          (_Float16)((O0[reg] * e0 + sm.ep.O[g][q_r][l31] * e1) * inv);
      ctxh[base + 32 + l31] =
          (_Float16)((O1[reg] * e0 + sm.ep.O[g][q_r][32 + l31] * e1) * inv);
    }
  }
}

// ---------------------------------------------------------------------------
extern "C" void kernel_launch(void* const* d_in, const int* in_sizes, int n_in,
                              void* d_out, int out_size, void* d_ws, size_t ws_size,
                              hipStream_t stream) {
  const float* feats = (const float*)d_in[0];
  const float* mask  = (const float*)d_in[1];
  const float* wq    = (const float*)d_in[2];
  const float* bq    = (const float*)d_in[3];
  const float* wk    = (const float*)d_in[4];
  const float* bk    = (const float*)d_in[5];
  const float* wv    = (const float*)d_in[6];
  const float* bv    = (const float*)d_in[7];
  const float* wo    = (const float*)d_in[8];
  const float* bo    = (const float*)d_in[9];

  char* ws = (char*)d_ws;
  const size_t MB = (size_t)1 << 20;
  _Float16* fh    = (_Float16*)(ws);             // 8 MB
  _Float16* wh3   = (_Float16*)(ws + 8  * MB);   // 6 MB
  _Float16* woh   = (_Float16*)(ws + 14 * MB);   // 2 MB
  _Float16* qb    = (_Float16*)(ws + 16 * MB);   // 8 MB
  _Float16* kb    = (_Float16*)(ws + 24 * MB);   // 8 MB
  _Float16* vtb   = (_Float16*)(ws + 32 * MB);   // 8 MB
  _Float16* ctxh  = (_Float16*)(ws + 40 * MB);   // 8 MB
  unsigned int* mflag = (unsigned int*)(ws + 48 * MB);

  float* out   = (float*)d_out;
  float* gated = out + 4194304;

  (void)hipMemsetAsync(mflag, 0, 4, stream);

  prep<<<8192, 256, 0, stream>>>(feats, wq, wk, wv, wo, fh, wh3, woh);

  gemm_qkv<<<dim3(NROWS / 128, 3072 / 128), 256, 0, stream>>>(
      fh, wh3, bq, bk, bv, qb, kb, vtb, mask, mflag);

  attn_mfma<<<Bc * Hc * (Sc / QB), 512, 0, stream>>>(qb, kb, vtb, mask, mflag, ctxh);

  gemm_wo<<<dim3(NROWS / 64, Dc / 128), 256, 0, stream>>>(
      ctxh, woh, bo, out, gated, feats);
}

// Round 23
// 182.646 us; speedup vs baseline: 1.1464x; 1.1464x over previous
//
#include <hip/hip_runtime.h>

#define Bc 2
#define Sc 2048
#define Dc 1024
#define Hc 16
#define HDc 64
#define NROWS 4096  // B*S
#define LOG2E 1.44269504f

typedef __attribute__((ext_vector_type(8))) _Float16 f16x8;
typedef __attribute__((ext_vector_type(4))) _Float16 f16x4;
typedef __attribute__((ext_vector_type(2))) __fp16 fp16v2;
typedef __attribute__((ext_vector_type(4))) float f32x4;
typedef __attribute__((ext_vector_type(16))) float f32x16;

__device__ __forceinline__ float ex2(float x) {
  return __builtin_amdgcn_exp2f(x);   // single v_exp_f32
}

// ---------------------------------------------------------------------------
// prep: fused fp32->f16 convert (feats, wq, wk, wv, wo).
// ---------------------------------------------------------------------------
__global__ __launch_bounds__(256)
void prep(const float* __restrict__ f,  const float* __restrict__ wq,
          const float* __restrict__ wk, const float* __restrict__ wv,
          const float* __restrict__ wo_,
          _Float16* __restrict__ fh, _Float16* __restrict__ wh3,
          _Float16* __restrict__ woh)
{
  int blk = blockIdx.x;
  const float* src; _Float16* hi; int base;
  if (blk < 4096)      { src = f;   hi = fh;            base = blk; }
  else if (blk < 5120) { src = wq;  hi = wh3;           base = blk - 4096; }
  else if (blk < 6144) { src = wk;  hi = wh3 + 1048576; base = blk - 5120; }
  else if (blk < 7168) { src = wv;  hi = wh3 + 2097152; base = blk - 6144; }
  else                 { src = wo_; hi = woh;           base = blk - 7168; }
  int i = base * 256 + threadIdx.x;
  float4 v = reinterpret_cast<const float4*>(src)[i];
  f16x4 h;
  h[0] = (_Float16)v.x; h[1] = (_Float16)v.y;
  h[2] = (_Float16)v.z; h[3] = (_Float16)v.w;
  reinterpret_cast<f16x4*>(hi)[i] = h;
}

// ---------------------------------------------------------------------------
// Fused QKV f16 GEMM + mask zero-scan preamble (hidden under compute).
// ---------------------------------------------------------------------------
__global__ __launch_bounds__(256, 4)
void gemm_qkv(const _Float16* __restrict__ Ah, const _Float16* __restrict__ Wh,
              const float* __restrict__ bq, const float* __restrict__ bk,
              const float* __restrict__ bv,
              _Float16* __restrict__ qb, _Float16* __restrict__ kb,
              _Float16* __restrict__ vtb,
              const float* __restrict__ mask, unsigned int* __restrict__ flag)
{
  __shared__ _Float16 Ash[128][40];
  __shared__ _Float16 Wsh[128][40];

  const int tid  = threadIdx.x;
  const int lane = tid & 63, wid = tid >> 6;
  const int l15  = lane & 15, l4 = lane >> 4;
  const int wr   = wid >> 1, wc = wid & 1;
  const int arow0 = blockIdx.x * 128;
  const int wrow0 = blockIdx.y * 128;

  {
    const int nthr = 768 * 256;
    int gtid = (blockIdx.y * gridDim.x + blockIdx.x) * 256 + tid;
    bool nz = false;
    for (int i = gtid; i < 2097152; i += nthr) {
      float4 mv = reinterpret_cast<const float4*>(mask)[i];
      nz = nz || (mv.x != 0.f) || (mv.y != 0.f) || (mv.z != 0.f) || (mv.w != 0.f);
    }
    if (__any(nz)) {
      if (lane == 0) atomicOr(flag, 1u);
    }
  }

  f32x4 acc[4][4];
#pragma unroll
  for (int m = 0; m < 4; ++m)
#pragma unroll
    for (int n = 0; n < 4; ++n) acc[m][n] = f32x4{0.f, 0.f, 0.f, 0.f};

  for (int k0 = 0; k0 < Dc; k0 += 32) {
    __syncthreads();
#pragma unroll
    for (int p = 0; p < 2; ++p) {
      int e = tid + 256 * p;
      int r = e >> 2, c8 = (e & 3) * 8;
      *reinterpret_cast<uint4*>(&Ash[r][c8]) =
          *reinterpret_cast<const uint4*>(Ah + (size_t)(arow0 + r) * Dc + k0 + c8);
      *reinterpret_cast<uint4*>(&Wsh[r][c8]) =
          *reinterpret_cast<const uint4*>(Wh + (size_t)(wrow0 + r) * Dc + k0 + c8);
    }
    __syncthreads();

    f16x8 bh[4];
#pragma unroll
    for (int n = 0; n < 4; ++n)
      bh[n] = *reinterpret_cast<const f16x8*>(&Wsh[wc * 64 + n * 16 + l15][l4 * 8]);
#pragma unroll
    for (int m = 0; m < 4; ++m) {
      f16x8 ah = *reinterpret_cast<const f16x8*>(&Ash[wr * 64 + m * 16 + l15][l4 * 8]);
#pragma unroll
      for (int n = 0; n < 4; ++n)
        acc[m][n] = __builtin_amdgcn_mfma_f32_16x16x32_f16(ah, bh[n], acc[m][n], 0, 0, 0);
    }
  }

#pragma unroll
  for (int m = 0; m < 4; ++m) {
#pragma unroll
    for (int n = 0; n < 4; ++n) {
      int cbase = wrow0 + wc * 64 + n * 16;
      int seg = cbase >> 10;
      int o = (cbase & 1023) + l15;
      int h = o >> 6, hd = o & 63;
      const float* bias = (seg == 0) ? bq : ((seg == 1) ? bk : bv);
      float bval = bias[o];
      float alpha = (seg == 0) ? (0.125f * LOG2E) : 1.0f;
      int r0 = arow0 + wr * 64 + m * 16 + l4 * 4;
      int b = r0 >> 11, s0 = r0 & (Sc - 1);
      if (seg == 2) {
        f16x4 pk;
#pragma unroll
        for (int reg = 0; reg < 4; ++reg)
          pk[reg] = (_Float16)((acc[m][n][reg] + bval) * alpha);
        *reinterpret_cast<f16x4*>(
            &vtb[(((size_t)b * Hc + h) * HDc + hd) * Sc + s0]) = pk;
      } else {
        _Float16* dst = (seg == 0) ? qb : kb;
#pragma unroll
        for (int reg = 0; reg < 4; ++reg) {
          float val = (acc[m][n][reg] + bval) * alpha;
          dst[(((size_t)b * Hc + h) * Sc + (s0 + reg)) * HDc + hd] = (_Float16)val;
        }
      }
    }
  }
}

// ---------------------------------------------------------------------------
// Output GEMM.
// ---------------------------------------------------------------------------
__global__ __launch_bounds__(256, 4)
void gemm_wo(const _Float16* __restrict__ Ah, const _Float16* __restrict__ Wh,
             const float* __restrict__ bias,
             float* __restrict__ out0, float* __restrict__ out1,
             const float* __restrict__ feats)
{
  __shared__ _Float16 Ash[64][40];
  __shared__ _Float16 Wsh[128][40];

  const int tid  = threadIdx.x;
  const int lane = tid & 63, wid = tid >> 6;
  const int l15  = lane & 15, l4 = lane >> 4;
  const int wr   = wid >> 1, wc = wid & 1;
  const int arow0 = blockIdx.x * 64;
  const int wrow0 = blockIdx.y * 128;

  f32x4 acc[2][4];
#pragma unroll
  for (int m = 0; m < 2; ++m)
#pragma unroll
    for (int n = 0; n < 4; ++n) acc[m][n] = f32x4{0.f, 0.f, 0.f, 0.f};

  for (int k0 = 0; k0 < Dc; k0 += 32) {
    __syncthreads();
    {
      int r = tid >> 2, c8 = (tid & 3) * 8;
      *reinterpret_cast<uint4*>(&Ash[r][c8]) =
          *reinterpret_cast<const uint4*>(Ah + (size_t)(arow0 + r) * Dc + k0 + c8);
    }
#pragma unroll
    for (int p = 0; p < 2; ++p) {
      int e = tid + 256 * p;
      int r = e >> 2, c8 = (e & 3) * 8;
      *reinterpret_cast<uint4*>(&Wsh[r][c8]) =
          *reinterpret_cast<const uint4*>(Wh + (size_t)(wrow0 + r) * Dc + k0 + c8);
    }
    __syncthreads();

    f16x8 bh[4];
#pragma unroll
    for (int n = 0; n < 4; ++n)
      bh[n] = *reinterpret_cast<const f16x8*>(&Wsh[wc * 64 + n * 16 + l15][l4 * 8]);
#pragma unroll
    for (int m = 0; m < 2; ++m) {
      f16x8 ah = *reinterpret_cast<const f16x8*>(&Ash[wr * 32 + m * 16 + l15][l4 * 8]);
#pragma unroll
      for (int n = 0; n < 4; ++n)
        acc[m][n] = __builtin_amdgcn_mfma_f32_16x16x32_f16(ah, bh[n], acc[m][n], 0, 0, 0);
    }
  }

#pragma unroll
  for (int m = 0; m < 2; ++m) {
#pragma unroll
    for (int n = 0; n < 4; ++n) {
      int c = wrow0 + wc * 64 + n * 16 + l15;
      float bval = bias[c];
#pragma unroll
      for (int reg = 0; reg < 4; ++reg) {
        int r = arow0 + wr * 32 + m * 16 + l4 * 4 + reg;
        float val = acc[m][n][reg] + bval;
        out1[(size_t)r * Dc + c] = val;
        out0[(size_t)r * Dc + c] = feats[(size_t)r * Dc + c] * val;
      }
    }
  }
}

// ---------------------------------------------------------------------------
// Flash attention, 32x32x16 f16 MFMA, INTRA-BLOCK KV-SPLIT (8 waves, 512thr).
// FIX vs round 22: __launch_bounds__(512, 2) -> VGPR cap 128 (no spill);
// 2 blocks/CU x 8 waves = 16 waves/CU.
// ---------------------------------------------------------------------------
#define QB 128
#define KB 64
#define NTH 16   // KV tiles per half

__global__ __launch_bounds__(512, 2)
void attn_mfma(const _Float16* __restrict__ q,
               const _Float16* __restrict__ k,
               const _Float16* __restrict__ vt,
               const float* __restrict__ mask,
               const unsigned int* __restrict__ mflag,
               _Float16* __restrict__ ctxh)
{
  __shared__ union {
    struct { _Float16 K[2][2][KB * 64]; _Float16 V[2][2][HDc * 64]; } kv;
    struct { float O[4][32][64]; float m0[4][32]; float l0_[4][32];
             float m1[4][32]; float l1_[4][32]; } ep;
  } sm;   // 64 KB

  const int tid  = threadIdx.x;
  const int lane = tid & 63;
  const int wq8  = tid >> 6;                 // 0..7
  const int g    = wq8 & 3;                  // q-row group (32 rows)
  const int half = wq8 >> 2;                 // KV half
  const int l31  = lane & 31;
  const int hi   = lane >> 5;

  const int nqb  = Sc / QB;                  // 16; grid = 512 = 8 XCD x 64
  const int bid  = blockIdx.x;
  const int swz  = (bid & 7) * 64 + (bid >> 3);   // XCD-chunked, bijective
  const int head = swz / nqb;
  const int q0   = (swz % nqb) * QB;
  const int b    = head / Hc;
  const int h    = head % Hc;
  const int kvb  = half * (Sc / 2);          // 0 or 1024

  const bool use_mask = (*mflag != 0u);

  const _Float16* kbase  = k  + (size_t)head * Sc * HDc;
  const _Float16* vtbase = vt + (size_t)head * HDc * Sc;
  const _Float16* qbase  = q  + ((size_t)head * Sc + q0 + g * 32 + l31) * HDc;
  const float*    mlh    = mask + ((size_t)b * Sc + q0 + g * 32 + l31) * Sc
                           + kvb + 4 * hi;

  // staging: 256 threads per half; each stages 2 chunks for K and V
  const int tidh = tid & 255;
  const int r0s = tidh >> 3, cs = tidh & 7;
  const int r1s = r0s + 32;
  const int so0 = r0s * 64 + ((cs ^ (r0s & 7)) * 8);
  const int so1 = r1s * 64 + ((cs ^ (r1s & 7)) * 8);

  f16x8 qf[4];
#pragma unroll
  for (int c = 0; c < 4; ++c)
    qf[c] = *reinterpret_cast<const f16x8*>(qbase + hi * 8 + 16 * c);

  f16x8 ones;
#pragma unroll
  for (int i = 0; i < 8; ++i) ones[i] = (_Float16)1.0f;

  f32x16 O0, O1, lacc;
#pragma unroll
  for (int i = 0; i < 16; ++i) { O0[i] = 0.f; O1[i] = 0.f; lacc[i] = 0.f; }
  float m_q = -3e38f;

  *reinterpret_cast<uint4*>(&sm.kv.K[half][0][so0]) =
      *reinterpret_cast<const uint4*>(kbase + (size_t)(kvb + r0s) * HDc + cs * 8);
  *reinterpret_cast<uint4*>(&sm.kv.K[half][0][so1]) =
      *reinterpret_cast<const uint4*>(kbase + (size_t)(kvb + r1s) * HDc + cs * 8);
  *reinterpret_cast<uint4*>(&sm.kv.V[half][0][so0]) =
      *reinterpret_cast<const uint4*>(vtbase + (size_t)r0s * Sc + kvb + cs * 8);
  *reinterpret_cast<uint4*>(&sm.kv.V[half][0][so1]) =
      *reinterpret_cast<const uint4*>(vtbase + (size_t)r1s * Sc + kvb + cs * 8);
  float4 mpf[8];
  if (use_mask) {
#pragma unroll
    for (int t2 = 0; t2 < 2; ++t2)
#pragma unroll
      for (int j = 0; j < 4; ++j)
        mpf[t2 * 4 + j] = *reinterpret_cast<const float4*>(mlh + 32 * t2 + 8 * j);
  }

  for (int kt = 0; kt < NTH; ++kt) {
    const int k0 = kt * KB;                  // offset within this half
    const int cur = kt & 1, nxt = cur ^ 1;
    __syncthreads();

    uint4 kr0, kr1, vr0, vr1;
    const bool pf = (kt + 1) < NTH;
    if (pf) {
      const int k1 = kvb + k0 + KB;
      kr0 = *reinterpret_cast<const uint4*>(kbase + (size_t)(k1 + r0s) * HDc + cs * 8);
      kr1 = *reinterpret_cast<const uint4*>(kbase + (size_t)(k1 + r1s) * HDc + cs * 8);
      vr0 = *reinterpret_cast<const uint4*>(vtbase + (size_t)r0s * Sc + k1 + cs * 8);
      vr1 = *reinterpret_cast<const uint4*>(vtbase + (size_t)r1s * Sc + k1 + cs * 8);
    }

    f32x16 s[2];
    __builtin_amdgcn_s_setprio(1);
#pragma unroll
    for (int t2 = 0; t2 < 2; ++t2) {
      f32x16 acc;
#pragma unroll
      for (int i = 0; i < 16; ++i) acc[i] = 0.f;
      const int krow = t2 * 32 + l31;
#pragma unroll
      for (int c = 0; c < 4; ++c) {
        const int ofs = krow * 64 + (((2 * c + hi) ^ (krow & 7)) * 8);
        acc = __builtin_amdgcn_mfma_f32_32x32x16_f16(
            *reinterpret_cast<const f16x8*>(&sm.kv.K[half][cur][ofs]), qf[c],
            acc, 0, 0, 0);
      }
      s[t2] = acc;
    }
    __builtin_amdgcn_s_setprio(0);

    if (use_mask) {
#pragma unroll
      for (int t2 = 0; t2 < 2; ++t2)
#pragma unroll
        for (int j = 0; j < 4; ++j) {
          float4 mv = mpf[t2 * 4 + j];
          s[t2][4 * j + 0] += mv.x * LOG2E; s[t2][4 * j + 1] += mv.y * LOG2E;
          s[t2][4 * j + 2] += mv.z * LOG2E; s[t2][4 * j + 3] += mv.w * LOG2E;
        }
      if (pf) {
#pragma unroll
        for (int t2 = 0; t2 < 2; ++t2)
#pragma unroll
          for (int j = 0; j < 4; ++j)
            mpf[t2 * 4 + j] = *reinterpret_cast<const float4*>(
                mlh + (k0 + KB) + 32 * t2 + 8 * j);
      }
    }

    // tree-max over this lane's 32 scores
    float t0_[8];
#pragma unroll
    for (int i = 0; i < 8; ++i)
      t0_[i] = fmaxf(fmaxf(s[0][2 * i], s[0][2 * i + 1]),
                     fmaxf(s[1][2 * i], s[1][2 * i + 1]));
    float t1_0 = fmaxf(fmaxf(t0_[0], t0_[1]), fmaxf(t0_[2], t0_[3]));
    float t1_1 = fmaxf(fmaxf(t0_[4], t0_[5]), fmaxf(t0_[6], t0_[7]));
    float lm = fmaxf(t1_0, t1_1);

    if (!__all(lm - m_q <= 8.0f * LOG2E)) {
      float vm = fmaxf(lm, __shfl_xor(lm, 32));
      float mn = fmaxf(m_q, vm);
      float cc = ex2(m_q - mn);
      m_q = mn;
#pragma unroll
      for (int reg = 0; reg < 16; ++reg) {
        int q_r = (reg & 3) + 8 * (reg >> 2) + 4 * hi;
        float ccr = __shfl(cc, q_r);
        O0[reg] *= ccr; O1[reg] *= ccr; lacc[reg] *= ccr;
      }
    }

    __builtin_amdgcn_s_setprio(1);
#pragma unroll
    for (int c = 0; c < 4; ++c) {
      const int t2 = c >> 1, rb = (c & 1) * 8;
      float p0 = ex2(s[t2][rb + 0] - m_q);
      float p1 = ex2(s[t2][rb + 1] - m_q);
      float p2 = ex2(s[t2][rb + 2] - m_q);
      float p3 = ex2(s[t2][rb + 3] - m_q);
      float p4 = ex2(s[t2][rb + 4] - m_q);
      float p5 = ex2(s[t2][rb + 5] - m_q);
      float p6 = ex2(s[t2][rb + 6] - m_q);
      float p7 = ex2(s[t2][rb + 7] - m_q);
      union { fp16v2 h; unsigned int u; } w0, w1, w2, w3;
      w0.h = __builtin_amdgcn_cvt_pkrtz(p0, p1);
      w1.h = __builtin_amdgcn_cvt_pkrtz(p2, p3);
      w2.h = __builtin_amdgcn_cvt_pkrtz(p4, p5);
      w3.h = __builtin_amdgcn_cvt_pkrtz(p6, p7);
      unsigned int u0 = w0.u, u1 = w1.u, u2 = w2.u, u3 = w3.u;
      asm("v_permlane32_swap_b32 %0, %1" : "+v"(u0), "+v"(u2));
      asm("v_permlane32_swap_b32 %0, %1" : "+v"(u1), "+v"(u3));
      union { unsigned int u[4]; f16x8 f; } pa;
      pa.u[0] = u0; pa.u[1] = u1; pa.u[2] = u2; pa.u[3] = u3;

      lacc = __builtin_amdgcn_mfma_f32_32x32x16_f16(pa.f, ones, lacc, 0, 0, 0);
      const int vofs = l31 * 64 + (((2 * c + hi) ^ (l31 & 7)) * 8);
      O0 = __builtin_amdgcn_mfma_f32_32x32x16_f16(
          pa.f, *reinterpret_cast<const f16x8*>(&sm.kv.V[half][cur][vofs]),
          O0, 0, 0, 0);
      O1 = __builtin_amdgcn_mfma_f32_32x32x16_f16(
          pa.f, *reinterpret_cast<const f16x8*>(&sm.kv.V[half][cur][vofs + 32 * 64]),
          O1, 0, 0, 0);
    }
    __builtin_amdgcn_s_setprio(0);

    if (pf) {
      *reinterpret_cast<uint4*>(&sm.kv.K[half][nxt][so0]) = kr0;
      *reinterpret_cast<uint4*>(&sm.kv.K[half][nxt][so1]) = kr1;
      *reinterpret_cast<uint4*>(&sm.kv.V[half][nxt][so0]) = vr0;
      *reinterpret_cast<uint4*>(&sm.kv.V[half][nxt][so1]) = vr1;
    }
  }

  // -------- intra-block combine of the two KV halves --------
  __syncthreads();   // all waves done reading kv region

  if (hi == 0) {
    if (half == 0) sm.ep.m0[g][l31] = m_q; else sm.ep.m1[g][l31] = m_q;
  }
  if (l31 == 0) {
#pragma unroll
    for (int reg = 0; reg < 16; ++reg) {
      int q_r = (reg & 3) + 8 * (reg >> 2) + 4 * hi;
      if (half == 0) sm.ep.l0_[g][q_r] = lacc[reg];
      else           sm.ep.l1_[g][q_r] = lacc[reg];
    }
  }
  if (half == 1) {
#pragma unroll
    for (int reg = 0; reg < 16; ++reg) {
      int q_r = (reg & 3) + 8 * (reg >> 2) + 4 * hi;
      sm.ep.O[g][q_r][l31]      = O0[reg];
      sm.ep.O[g][q_r][32 + l31] = O1[reg];
    }
  }
  __syncthreads();

  if (half == 0) {
#pragma unroll
    for (int reg = 0; reg < 16; ++reg) {
      int q_r = (reg & 3) + 8 * (reg >> 2) + 4 * hi;
      float m0v = sm.ep.m0[g][q_r], m1v = sm.ep.m1[g][q_r];
      float l0v = lacc[reg],        l1v = sm.ep.l1_[g][q_r];
      float mm = fmaxf(m0v, m1v);
      float e0 = ex2(m0v - mm), e1 = ex2(m1v - mm);
      float inv = 1.0f / (l0v * e0 + l1v * e1);
      int row = q0 + g * 32 + q_r;
      size_t base = ((size_t)b * Sc + row) * Dc + h * HDc;
      ctxh[base + l31] =
          (_Float16)((O0[reg] * e0 + sm.ep.O[g][q_r][l31] * e1) * inv);
      ctxh[base + 32 + l31] =
          (_Float16)((O1[reg] * e0 + sm.ep.O[g][q_r][32 + l31] * e1) * inv);
    }
  }
}

// ---------------------------------------------------------------------------
extern "C" void kernel_launch(void* const* d_in, const int* in_sizes, int n_in,
                              void* d_out, int out_size, void* d_ws, size_t ws_size,
                              hipStream_t stream) {
  const float* feats = (const float*)d_in[0];
  const float* mask  = (const float*)d_in[1];
  const float* wq    = (const float*)d_in[2];
  const float* bq    = (const float*)d_in[3];
  const float* wk    = (const float*)d_in[4];
  const float* bk    = (const float*)d_in[5];
  const float* wv    = (const float*)d_in[6];
  const float* bv    = (const float*)d_in[7];
  const float* wo    = (const float*)d_in[8];
  const float* bo    = (const float*)d_in[9];

  char* ws = (char*)d_ws;
  const size_t MB = (size_t)1 << 20;
  _Float16* fh    = (_Float16*)(ws);             // 8 MB
  _Float16* wh3   = (_Float16*)(ws + 8  * MB);   // 6 MB
  _Float16* woh   = (_Float16*)(ws + 14 * MB);   // 2 MB
  _Float16* qb    = (_Float16*)(ws + 16 * MB);   // 8 MB
  _Float16* kb    = (_Float16*)(ws + 24 * MB);   // 8 MB
  _Float16* vtb   = (_Float16*)(ws + 32 * MB);   // 8 MB
  _Float16* ctxh  = (_Float16*)(ws + 40 * MB);   // 8 MB
  unsigned int* mflag = (unsigned int*)(ws + 48 * MB);

  float* out   = (float*)d_out;
  float* gated = out + 4194304;

  (void)hipMemsetAsync(mflag, 0, 4, stream);

  prep<<<8192, 256, 0, stream>>>(feats, wq, wk, wv, wo, fh, wh3, woh);

  gemm_qkv<<<dim3(NROWS / 128, 3072 / 128), 256, 0, stream>>>(
      fh, wh3, bq, bk, bv, qb, kb, vtb, mask, mflag);

  attn_mfma<<<Bc * Hc * (Sc / QB), 512, 0, stream>>>(qb, kb, vtb, mask, mflag, ctxh);

  gemm_wo<<<dim3(NROWS / 64, Dc / 128), 256, 0, stream>>>(
      ctxh, woh, bo, out, gated, feats);
}

// Round 24
// 143.610 us; speedup vs baseline: 1.4580x; 1.2718x over previous
//
#include <hip/hip_runtime.h>

#define Bc 2
#define Sc 2048
#define Dc 1024
#define Hc 16
#define HDc 64
#define NROWS 4096  // B*S
#define LOG2E 1.44269504f

typedef __attribute__((ext_vector_type(8))) _Float16 f16x8;
typedef __attribute__((ext_vector_type(4))) _Float16 f16x4;
typedef __attribute__((ext_vector_type(2))) __fp16 fp16v2;
typedef __attribute__((ext_vector_type(4))) float f32x4;
typedef __attribute__((ext_vector_type(16))) float f32x16;

__device__ __forceinline__ float ex2(float x) {
  return __builtin_amdgcn_exp2f(x);   // single v_exp_f32
}

// ---------------------------------------------------------------------------
// prep: fused fp32->f16 convert (feats, wq, wk, wv, wo) + mask zero-scan.
// ---------------------------------------------------------------------------
__global__ __launch_bounds__(256)
void prep(const float* __restrict__ f,  const float* __restrict__ wq,
          const float* __restrict__ wk, const float* __restrict__ wv,
          const float* __restrict__ wo_, const float* __restrict__ mask,
          _Float16* __restrict__ fh, _Float16* __restrict__ wh3,
          _Float16* __restrict__ woh, unsigned int* __restrict__ flag)
{
  int blk = blockIdx.x;
  const float* src; _Float16* hi; int base;
  if (blk < 4096)      { src = f;   hi = fh;            base = blk; }
  else if (blk < 5120) { src = wq;  hi = wh3;           base = blk - 4096; }
  else if (blk < 6144) { src = wk;  hi = wh3 + 1048576; base = blk - 5120; }
  else if (blk < 7168) { src = wv;  hi = wh3 + 2097152; base = blk - 6144; }
  else                 { src = wo_; hi = woh;           base = blk - 7168; }
  int i = base * 256 + threadIdx.x;
  float4 v = reinterpret_cast<const float4*>(src)[i];
  f16x4 h;
  h[0] = (_Float16)v.x; h[1] = (_Float16)v.y;
  h[2] = (_Float16)v.z; h[3] = (_Float16)v.w;
  reinterpret_cast<f16x4*>(hi)[i] = h;

  int g = blk * 256 + threadIdx.x;
  float4 mv = reinterpret_cast<const float4*>(mask)[g];
  bool nz = (mv.x != 0.f) || (mv.y != 0.f) || (mv.z != 0.f) || (mv.w != 0.f);
  if (__any(nz)) {
    if ((threadIdx.x & 63) == 0) atomicOr(flag, 1u);
  }
}

// ---------------------------------------------------------------------------
// Fused QKV f16 GEMM. q-scale folds in LOG2E (scores in log2 domain).
// ---------------------------------------------------------------------------
__global__ __launch_bounds__(256, 4)
void gemm_qkv(const _Float16* __restrict__ Ah, const _Float16* __restrict__ Wh,
              const float* __restrict__ bq, const float* __restrict__ bk,
              const float* __restrict__ bv,
              _Float16* __restrict__ qb, _Float16* __restrict__ kb,
              _Float16* __restrict__ vtb)
{
  __shared__ _Float16 Ash[128][40];
  __shared__ _Float16 Wsh[128][40];

  const int tid  = threadIdx.x;
  const int lane = tid & 63, wid = tid >> 6;
  const int l15  = lane & 15, l4 = lane >> 4;
  const int wr   = wid >> 1, wc = wid & 1;
  const int arow0 = blockIdx.x * 128;
  const int wrow0 = blockIdx.y * 128;

  f32x4 acc[4][4];
#pragma unroll
  for (int m = 0; m < 4; ++m)
#pragma unroll
    for (int n = 0; n < 4; ++n) acc[m][n] = f32x4{0.f, 0.f, 0.f, 0.f};

  for (int k0 = 0; k0 < Dc; k0 += 32) {
    __syncthreads();
#pragma unroll
    for (int p = 0; p < 2; ++p) {
      int e = tid + 256 * p;
      int r = e >> 2, c8 = (e & 3) * 8;
      *reinterpret_cast<uint4*>(&Ash[r][c8]) =
          *reinterpret_cast<const uint4*>(Ah + (size_t)(arow0 + r) * Dc + k0 + c8);
      *reinterpret_cast<uint4*>(&Wsh[r][c8]) =
          *reinterpret_cast<const uint4*>(Wh + (size_t)(wrow0 + r) * Dc + k0 + c8);
    }
    __syncthreads();

    f16x8 bh[4];
#pragma unroll
    for (int n = 0; n < 4; ++n)
      bh[n] = *reinterpret_cast<const f16x8*>(&Wsh[wc * 64 + n * 16 + l15][l4 * 8]);
#pragma unroll
    for (int m = 0; m < 4; ++m) {
      f16x8 ah = *reinterpret_cast<const f16x8*>(&Ash[wr * 64 + m * 16 + l15][l4 * 8]);
#pragma unroll
      for (int n = 0; n < 4; ++n)
        acc[m][n] = __builtin_amdgcn_mfma_f32_16x16x32_f16(ah, bh[n], acc[m][n], 0, 0, 0);
    }
  }

#pragma unroll
  for (int m = 0; m < 4; ++m) {
#pragma unroll
    for (int n = 0; n < 4; ++n) {
      int cbase = wrow0 + wc * 64 + n * 16;
      int seg = cbase >> 10;
      int o = (cbase & 1023) + l15;
      int h = o >> 6, hd = o & 63;
      const float* bias = (seg == 0) ? bq : ((seg == 1) ? bk : bv);
      float bval = bias[o];
      float alpha = (seg == 0) ? (0.125f * LOG2E) : 1.0f;
      int r0 = arow0 + wr * 64 + m * 16 + l4 * 4;
      int b = r0 >> 11, s0 = r0 & (Sc - 1);
      if (seg == 2) {
        f16x4 pk;
#pragma unroll
        for (int reg = 0; reg < 4; ++reg)
          pk[reg] = (_Float16)((acc[m][n][reg] + bval) * alpha);
        *reinterpret_cast<f16x4*>(
            &vtb[(((size_t)b * Hc + h) * HDc + hd) * Sc + s0]) = pk;
      } else {
        _Float16* dst = (seg == 0) ? qb : kb;
#pragma unroll
        for (int reg = 0; reg < 4; ++reg) {
          float val = (acc[m][n][reg] + bval) * alpha;
          dst[(((size_t)b * Hc + h) * Sc + (s0 + reg)) * HDc + hd] = (_Float16)val;
        }
      }
    }
  }
}

// ---------------------------------------------------------------------------
// Output GEMM.
// ---------------------------------------------------------------------------
__global__ __launch_bounds__(256, 4)
void gemm_wo(const _Float16* __restrict__ Ah, const _Float16* __restrict__ Wh,
             const float* __restrict__ bias,
             float* __restrict__ out0, float* __restrict__ out1,
             const float* __restrict__ feats)
{
  __shared__ _Float16 Ash[64][40];
  __shared__ _Float16 Wsh[128][40];

  const int tid  = threadIdx.x;
  const int lane = tid & 63, wid = tid >> 6;
  const int l15  = lane & 15, l4 = lane >> 4;
  const int wr   = wid >> 1, wc = wid & 1;
  const int arow0 = blockIdx.x * 64;
  const int wrow0 = blockIdx.y * 128;

  f32x4 acc[2][4];
#pragma unroll
  for (int m = 0; m < 2; ++m)
#pragma unroll
    for (int n = 0; n < 4; ++n) acc[m][n] = f32x4{0.f, 0.f, 0.f, 0.f};

  for (int k0 = 0; k0 < Dc; k0 += 32) {
    __syncthreads();
    {
      int r = tid >> 2, c8 = (tid & 3) * 8;
      *reinterpret_cast<uint4*>(&Ash[r][c8]) =
          *reinterpret_cast<const uint4*>(Ah + (size_t)(arow0 + r) * Dc + k0 + c8);
    }
#pragma unroll
    for (int p = 0; p < 2; ++p) {
      int e = tid + 256 * p;
      int r = e >> 2, c8 = (e & 3) * 8;
      *reinterpret_cast<uint4*>(&Wsh[r][c8]) =
          *reinterpret_cast<const uint4*>(Wh + (size_t)(wrow0 + r) * Dc + k0 + c8);
    }
    __syncthreads();

    f16x8 bh[4];
#pragma unroll
    for (int n = 0; n < 4; ++n)
      bh[n] = *reinterpret_cast<const f16x8*>(&Wsh[wc * 64 + n * 16 + l15][l4 * 8]);
#pragma unroll
    for (int m = 0; m < 2; ++m) {
      f16x8 ah = *reinterpret_cast<const f16x8*>(&Ash[wr * 32 + m * 16 + l15][l4 * 8]);
#pragma unroll
      for (int n = 0; n < 4; ++n)
        acc[m][n] = __builtin_amdgcn_mfma_f32_16x16x32_f16(ah, bh[n], acc[m][n], 0, 0, 0);
    }
  }

#pragma unroll
  for (int m = 0; m < 2; ++m) {
#pragma unroll
    for (int n = 0; n < 4; ++n) {
      int c = wrow0 + wc * 64 + n * 16 + l15;
      float bval = bias[c];
#pragma unroll
      for (int reg = 0; reg < 4; ++reg) {
        int r = arow0 + wr * 32 + m * 16 + l4 * 4 + reg;
        float val = acc[m][n][reg] + bval;
        out1[(size_t)r * Dc + c] = val;
        out0[(size_t)r * Dc + c] = feats[(size_t)r * Dc + c] * val;
      }
    }
  }
}

// ---------------------------------------------------------------------------
// Flash attention, 32x32x16 f16 MFMA — QB=128, 4 waves, grid 512,
// XCD-chunked swizzle, exp2-domain softmax, zero-mask fast path.
// (round-17 structure: best measured configuration)
// ---------------------------------------------------------------------------
#define QB 128
#define KB 64
#define NT (Sc / KB)

__global__ __launch_bounds__(256, 2)
void attn_mfma(const _Float16* __restrict__ q,
               const _Float16* __restrict__ k,
               const _Float16* __restrict__ vt,
               const float* __restrict__ mask,
               const unsigned int* __restrict__ mflag,
               _Float16* __restrict__ ctxh)
{
  __shared__ _Float16 Ks[2][KB * 64];        // [k-row][hd], XOR-swizzled
  __shared__ _Float16 Vs[2][HDc * 64];       // V^T [d][k], XOR-swizzled

  const int tid  = threadIdx.x;
  const int lane = tid & 63;
  const int wq   = tid >> 6;                 // wave 0..3
  const int l31  = lane & 31;
  const int hi   = lane >> 5;

  const int nqb  = Sc / QB;                  // 16; grid = 512 = 8 XCD x 64
  const int bid  = blockIdx.x;
  const int swz  = (bid & 7) * 64 + (bid >> 3);   // XCD-chunked, bijective
  const int head = swz / nqb;
  const int q0   = (swz % nqb) * QB;
  const int b    = head / Hc;
  const int h    = head % Hc;

  const bool use_mask = (*mflag != 0u);

  const _Float16* kbase  = k  + (size_t)head * Sc * HDc;
  const _Float16* vtbase = vt + (size_t)head * HDc * Sc;
  const _Float16* qbase  = q  + ((size_t)head * Sc + q0 + wq * 32 + l31) * HDc;
  const float*    ml     = mask + ((size_t)b * Sc + q0 + wq * 32 + l31) * Sc + 4 * hi;

  const int r0s = tid >> 3, cs = tid & 7;
  const int r1s = r0s + 32;
  const int so0 = r0s * 64 + ((cs ^ (r0s & 7)) * 8);
  const int so1 = r1s * 64 + ((cs ^ (r1s & 7)) * 8);

  f16x8 qf[4];
#pragma unroll
  for (int c = 0; c < 4; ++c)
    qf[c] = *reinterpret_cast<const f16x8*>(qbase + hi * 8 + 16 * c);

  f16x8 ones;
#pragma unroll
  for (int i = 0; i < 8; ++i) ones[i] = (_Float16)1.0f;

  f32x16 O0, O1, lacc;
#pragma unroll
  for (int i = 0; i < 16; ++i) { O0[i] = 0.f; O1[i] = 0.f; lacc[i] = 0.f; }
  float m_q = -3e38f;

  *reinterpret_cast<uint4*>(&Ks[0][so0]) =
      *reinterpret_cast<const uint4*>(kbase + (size_t)r0s * HDc + cs * 8);
  *reinterpret_cast<uint4*>(&Ks[0][so1]) =
      *reinterpret_cast<const uint4*>(kbase + (size_t)r1s * HDc + cs * 8);
  *reinterpret_cast<uint4*>(&Vs[0][so0]) =
      *reinterpret_cast<const uint4*>(vtbase + (size_t)r0s * Sc + cs * 8);
  *reinterpret_cast<uint4*>(&Vs[0][so1]) =
      *reinterpret_cast<const uint4*>(vtbase + (size_t)r1s * Sc + cs * 8);
  float4 mpf[8];
  if (use_mask) {
#pragma unroll
    for (int t2 = 0; t2 < 2; ++t2)
#pragma unroll
      for (int j = 0; j < 4; ++j)
        mpf[t2 * 4 + j] = *reinterpret_cast<const float4*>(ml + 32 * t2 + 8 * j);
  }

  for (int kt = 0; kt < NT; ++kt) {
    const int k0 = kt * KB;
    const int cur = kt & 1, nxt = cur ^ 1;
    __syncthreads();

    uint4 kr0, kr1, vr0, vr1;
    const bool pf = (kt + 1) < NT;
    if (pf) {
      const int k1 = k0 + KB;
      kr0 = *reinterpret_cast<const uint4*>(kbase + (size_t)(k1 + r0s) * HDc + cs * 8);
      kr1 = *reinterpret_cast<const uint4*>(kbase + (size_t)(k1 + r1s) * HDc + cs * 8);
      vr0 = *reinterpret_cast<const uint4*>(vtbase + (size_t)r0s * Sc + k1 + cs * 8);
      vr1 = *reinterpret_cast<const uint4*>(vtbase + (size_t)r1s * Sc + k1 + cs * 8);
    }

    f32x16 s[2];
    __builtin_amdgcn_s_setprio(1);
#pragma unroll
    for (int t2 = 0; t2 < 2; ++t2) {
      f32x16 acc;
#pragma unroll
      for (int i = 0; i < 16; ++i) acc[i] = 0.f;
      const int krow = t2 * 32 + l31;
#pragma unroll
      for (int c = 0; c < 4; ++c) {
        const int ofs = krow * 64 + (((2 * c + hi) ^ (krow & 7)) * 8);
        acc = __builtin_amdgcn_mfma_f32_32x32x16_f16(
            *reinterpret_cast<const f16x8*>(&Ks[cur][ofs]), qf[c], acc, 0, 0, 0);
      }
      s[t2] = acc;
    }
    __builtin_amdgcn_s_setprio(0);

    if (use_mask) {
#pragma unroll
      for (int t2 = 0; t2 < 2; ++t2)
#pragma unroll
        for (int j = 0; j < 4; ++j) {
          float4 mv = mpf[t2 * 4 + j];
          s[t2][4 * j + 0] += mv.x * LOG2E; s[t2][4 * j + 1] += mv.y * LOG2E;
          s[t2][4 * j + 2] += mv.z * LOG2E; s[t2][4 * j + 3] += mv.w * LOG2E;
        }
      if (pf) {
#pragma unroll
        for (int t2 = 0; t2 < 2; ++t2)
#pragma unroll
          for (int j = 0; j < 4; ++j)
            mpf[t2 * 4 + j] = *reinterpret_cast<const float4*>(
                ml + (k0 + KB) + 32 * t2 + 8 * j);
      }
    }

    float lm = s[0][0];
#pragma unroll
    for (int t2 = 0; t2 < 2; ++t2)
#pragma unroll
      for (int i = 0; i < 16; ++i) lm = fmaxf(lm, s[t2][i]);

    if (!__all(lm - m_q <= 8.0f * LOG2E)) {
      float vm = fmaxf(lm, __shfl_xor(lm, 32));
      float mn = fmaxf(m_q, vm);
      float cc = ex2(m_q - mn);
      m_q = mn;
#pragma unroll
      for (int reg = 0; reg < 16; ++reg) {
        int q_r = (reg & 3) + 8 * (reg >> 2) + 4 * hi;
        float ccr = __shfl(cc, q_r);
        O0[reg] *= ccr; O1[reg] *= ccr; lacc[reg] *= ccr;
      }
    }

    __builtin_amdgcn_s_setprio(1);
#pragma unroll
    for (int c = 0; c < 4; ++c) {
      const int t2 = c >> 1, rb = (c & 1) * 8;
      float p0 = ex2(s[t2][rb + 0] - m_q);
      float p1 = ex2(s[t2][rb + 1] - m_q);
      float p2 = ex2(s[t2][rb + 2] - m_q);
      float p3 = ex2(s[t2][rb + 3] - m_q);
      float p4 = ex2(s[t2][rb + 4] - m_q);
      float p5 = ex2(s[t2][rb + 5] - m_q);
      float p6 = ex2(s[t2][rb + 6] - m_q);
      float p7 = ex2(s[t2][rb + 7] - m_q);
      union { fp16v2 h; unsigned int u; } w0, w1, w2, w3;
      w0.h = __builtin_amdgcn_cvt_pkrtz(p0, p1);
      w1.h = __builtin_amdgcn_cvt_pkrtz(p2, p3);
      w2.h = __builtin_amdgcn_cvt_pkrtz(p4, p5);
      w3.h = __builtin_amdgcn_cvt_pkrtz(p6, p7);
      unsigned int u0 = w0.u, u1 = w1.u, u2 = w2.u, u3 = w3.u;
      asm("v_permlane32_swap_b32 %0, %1" : "+v"(u0), "+v"(u2));
      asm("v_permlane32_swap_b32 %0, %1" : "+v"(u1), "+v"(u3));
      union { unsigned int u[4]; f16x8 f; } pa;
      pa.u[0] = u0; pa.u[1] = u1; pa.u[2] = u2; pa.u[3] = u3;

      lacc = __builtin_amdgcn_mfma_f32_32x32x16_f16(pa.f, ones, lacc, 0, 0, 0);
      const int vofs = l31 * 64 + (((2 * c + hi) ^ (l31 & 7)) * 8);
      O0 = __builtin_amdgcn_mfma_f32_32x32x16_f16(
          pa.f, *reinterpret_cast<const f16x8*>(&Vs[cur][vofs]), O0, 0, 0, 0);
      O1 = __builtin_amdgcn_mfma_f32_32x32x16_f16(
          pa.f, *reinterpret_cast<const f16x8*>(&Vs[cur][vofs + 32 * 64]), O1, 0, 0, 0);
    }
    __builtin_amdgcn_s_setprio(0);

    if (pf) {
      *reinterpret_cast<uint4*>(&Ks[nxt][so0]) = kr0;
      *reinterpret_cast<uint4*>(&Ks[nxt][so1]) = kr1;
      *reinterpret_cast<uint4*>(&Vs[nxt][so0]) = vr0;
      *reinterpret_cast<uint4*>(&Vs[nxt][so1]) = vr1;
    }
  }

#pragma unroll
  for (int reg = 0; reg < 16; ++reg) {
    int q_r = (reg & 3) + 8 * (reg >> 2) + 4 * hi;
    float inv = 1.0f / lacc[reg];
    size_t rowbase = ((size_t)b * Sc + (q0 + wq * 32 + q_r)) * Dc + h * HDc;
    ctxh[rowbase + l31]      = (_Float16)(O0[reg] * inv);
    ctxh[rowbase + 32 + l31] = (_Float16)(O1[reg] * inv);
  }
}

// ---------------------------------------------------------------------------
extern "C" void kernel_launch(void* const* d_in, const int* in_sizes, int n_in,
                              void* d_out, int out_size, void* d_ws, size_t ws_size,
                              hipStream_t stream) {
  const float* feats = (const float*)d_in[0];
  const float* mask  = (const float*)d_in[1];
  const float* wq    = (const float*)d_in[2];
  const float* bq    = (const float*)d_in[3];
  const float* wk    = (const float*)d_in[4];
  const float* bk    = (const float*)d_in[5];
  const float* wv    = (const float*)d_in[6];
  const float* bv    = (const float*)d_in[7];
  const float* wo    = (const float*)d_in[8];
  const float* bo    = (const float*)d_in[9];

  char* ws = (char*)d_ws;
  const size_t MB = (size_t)1 << 20;
  _Float16* fh    = (_Float16*)(ws);             // 8 MB
  _Float16* wh3   = (_Float16*)(ws + 8  * MB);   // 6 MB
  _Float16* woh   = (_Float16*)(ws + 14 * MB);   // 2 MB
  _Float16* qb    = (_Float16*)(ws + 16 * MB);   // 8 MB
  _Float16* kb    = (_Float16*)(ws + 24 * MB);   // 8 MB
  _Float16* vtb   = (_Float16*)(ws + 32 * MB);   // 8 MB
  _Float16* ctxh  = (_Float16*)(ws + 40 * MB);   // 8 MB
  unsigned int* mflag = (unsigned int*)(ws + 48 * MB);

  float* out   = (float*)d_out;
  float* gated = out + 4194304;

  (void)hipMemsetAsync(mflag, 0, 4, stream);

  prep<<<8192, 256, 0, stream>>>(feats, wq, wk, wv, wo, mask,
                                 fh, wh3, woh, mflag);

  gemm_qkv<<<dim3(NROWS / 128, 3072 / 128), 256, 0, stream>>>(
      fh, wh3, bq, bk, bv, qb, kb, vtb);

  attn_mfma<<<Bc * Hc * (Sc / QB), 256, 0, stream>>>(qb, kb, vtb, mask, mflag, ctxh);

  gemm_wo<<<dim3(NROWS / 64, Dc / 128), 256, 0, stream>>>(
      ctxh, woh, bo, out, gated, feats);
}